// Round 4
// baseline (69.898 us; speedup 1.0000x reference)
//
#include <hip/hip_runtime.h>
#include <hip/hip_bf16.h>

// ObliviousDecisionLayer on MI355X.
// Reference semantics: einsum('bj,tdk->btd') has NO shared index ->
// decisions[b,t,d] = rowsum(inputs)[b] * rowsum(dw)[t,d].
// Leaf contraction folds: bit d of leaf index l: 0 -> dec[d], 1 -> 1-dec[d].
//
// R4 changes:
//  - __launch_bounds__(256, 1) on forest: open full VGPR budget (lf/m/res
//    arrays ~150 VGPRs; a default-occupancy register cap would spill to
//    scratch inside the 8x-unrolled loop).
//  - prep pre-scales leaves by 1/256 (folds the tree-mean) and pre-computes
//    the level-5 fold pairs D5=lf[i]-lf[i+32], B5=lf[i+32] (batch-invariant)
//    -> level 5 becomes 32 fma instead of 32 sub + 32 fma per batch row.

#define NUM_TREES 256
#define DEPTH 6
#define LEAVES 64
#define BATCH 4096
#define FEATURES 256
#define BPB 8  // batch rows per forest block

// ws layout (floats):
//   s_in @ 0      [4096]
//   sw_t @ 4096   [6][256]      sw_t[d][t] = rowsum(dw[t][d][:])
//   th_t @ 5632   [6][256]      th_t[d][t] = thr[t][d]
//   B5   @ 7168   [8][256]x4    B5[c][t] = leaf[t][32+4c..] * (1/256)
//   D5   @ 15360  [8][256]x4    D5[c][t] = (leaf[t][4c..] - leaf[t][32+4c..]) * (1/256)
#define WS_SIN  0
#define WS_SWT  4096
#define WS_THT  5632
#define WS_B5   7168
#define WS_D5   15360

// ---------------- Kernel 1: row sums + transposes ----------------
__global__ __launch_bounds__(256) void prep_kernel(
    const float* __restrict__ inputs,   // [4096][256]
    const float* __restrict__ dw,       // [1536][256]
    const float* __restrict__ thr,      // [256][6]
    const float* __restrict__ leaf,     // [256][64]
    float* __restrict__ ws)
{
    const int gw   = (blockIdx.x * blockDim.x + threadIdx.x) >> 6;
    const int lane = threadIdx.x & 63;
    const float scale = 1.0f / (float)NUM_TREES;

    if (gw < BATCH + NUM_TREES * DEPTH) {
        // row-sum of a 256-float row
        const float* src;
        float* dst;
        if (gw < BATCH) {
            src = inputs + (size_t)gw * FEATURES;
            dst = ws + WS_SIN + gw;
        } else {
            const int r = gw - BATCH;        // r = t*6 + d
            const int t = r / DEPTH;
            const int d = r - t * DEPTH;
            src = dw + (size_t)r * FEATURES;
            dst = ws + WS_SWT + d * NUM_TREES + t;
        }
        float4 v = reinterpret_cast<const float4*>(src)[lane];
        float s = (v.x + v.y) + (v.z + v.w);
#pragma unroll
        for (int off = 32; off > 0; off >>= 1)
            s += __shfl_down(s, off);
        if (lane == 0) *dst = s;
    } else if (gw < BATCH + NUM_TREES * DEPTH + 64) {
        // leaf transpose + scale + level-5 pre-fold
        // wave j: chunk c = j>>2 (0..15), trees t = (j&3)*64+lane
        const int j = gw - (BATCH + NUM_TREES * DEPTH);
        const int c = j >> 2;
        const int t = ((j & 3) << 6) | lane;
        const float4* lp = reinterpret_cast<const float4*>(leaf);
        if (c < 8) {
            // D5[c][t] = (chunk c - chunk c+8) * scale
            float4 va = lp[t * (LEAVES / 4) + c];
            float4 vb = lp[t * (LEAVES / 4) + c + 8];
            float4 d;
            d.x = (va.x - vb.x) * scale; d.y = (va.y - vb.y) * scale;
            d.z = (va.z - vb.z) * scale; d.w = (va.w - vb.w) * scale;
            reinterpret_cast<float4*>(ws + WS_D5)[c * NUM_TREES + t] = d;
        } else {
            // B5[c-8][t] = chunk c * scale
            float4 vb = lp[t * (LEAVES / 4) + c];
            float4 b;
            b.x = vb.x * scale; b.y = vb.y * scale;
            b.z = vb.z * scale; b.w = vb.w * scale;
            reinterpret_cast<float4*>(ws + WS_B5)[(c - 8) * NUM_TREES + t] = b;
        }
    } else {
        // threshold transpose: 24 waves cover 1536 elements
        const int j = gw - (BATCH + NUM_TREES * DEPTH + 64);
        const int idx = j * 64 + lane;       // = t*6 + d
        const int t = idx / DEPTH;
        const int d = idx - t * DEPTH;
        ws[WS_THT + d * NUM_TREES + t] = thr[idx];
    }
}

// ---------------- Kernel 2: per-(b,t) evaluation + tree-mean ----------------
__global__ __launch_bounds__(256, 1) void forest_kernel(
    const float* __restrict__ ws,
    float* __restrict__ out)            // [4096]
{
    const int t  = threadIdx.x;         // tree index, 0..255
    const int b0 = blockIdx.x * BPB;    // first batch row of this block

    // Per-tree constants — all loads wave-coalesced (stride-1 in t)
    float sw[DEPTH], th[DEPTH];
#pragma unroll
    for (int d = 0; d < DEPTH; ++d) {
        sw[d] = ws[WS_SWT + d * NUM_TREES + t];
        th[d] = ws[WS_THT + d * NUM_TREES + t];
    }
    float b5[32], d5[32];
#pragma unroll
    for (int c = 0; c < 8; ++c) {
        float4 vb = reinterpret_cast<const float4*>(ws + WS_B5)[c * NUM_TREES + t];
        float4 vd = reinterpret_cast<const float4*>(ws + WS_D5)[c * NUM_TREES + t];
        b5[4 * c + 0] = vb.x; b5[4 * c + 1] = vb.y;
        b5[4 * c + 2] = vb.z; b5[4 * c + 3] = vb.w;
        d5[4 * c + 0] = vd.x; d5[4 * c + 1] = vd.y;
        d5[4 * c + 2] = vd.z; d5[4 * c + 3] = vd.w;
    }

    float res[BPB];
#pragma unroll
    for (int bi = 0; bi < BPB; ++bi) {
        const float si = ws[WS_SIN + b0 + bi];  // block-uniform
        float dec[DEPTH];
#pragma unroll
        for (int d = 0; d < DEPTH; ++d) {
            const float x = fmaf(si, sw[d], th[d]);
            dec[d] = 1.0f / (1.0f + __expf(-x));  // sigmoid
        }
        // Fold leaves over bits 5..0: bit==0 picks dec[d], bit==1 picks 1-dec[d].
        // Level 5 uses pre-folded (diff, base): m = fma(dec5, D5, B5).
        float m[32];
#pragma unroll
        for (int i = 0; i < 32; ++i) m[i] = fmaf(dec[5], d5[i], b5[i]);
#pragma unroll
        for (int i = 0; i < 16; ++i) m[i] = fmaf(dec[4], m[i] - m[i + 16], m[i + 16]);
#pragma unroll
        for (int i = 0; i < 8; ++i)  m[i] = fmaf(dec[3], m[i] - m[i + 8],  m[i + 8]);
#pragma unroll
        for (int i = 0; i < 4; ++i)  m[i] = fmaf(dec[2], m[i] - m[i + 4],  m[i + 4]);
#pragma unroll
        for (int i = 0; i < 2; ++i)  m[i] = fmaf(dec[1], m[i] - m[i + 2],  m[i + 2]);
        res[bi] = fmaf(dec[0], m[0] - m[1], m[1]);
    }

    // Reduce res[bi] over 256 trees (4 waves) -> mean (1/256 pre-folded into leaves)
    __shared__ float red[4][BPB];
    const int lane = t & 63;
    const int wv   = t >> 6;
#pragma unroll
    for (int bi = 0; bi < BPB; ++bi) {
        float v = res[bi];
#pragma unroll
        for (int off = 32; off > 0; off >>= 1)
            v += __shfl_down(v, off);
        if (lane == 0) red[wv][bi] = v;
    }
    __syncthreads();
    if (t < BPB) {
        out[b0 + t] = red[0][t] + red[1][t] + red[2][t] + red[3][t];
    }
}

extern "C" void kernel_launch(void* const* d_in, const int* in_sizes, int n_in,
                              void* d_out, int out_size, void* d_ws, size_t ws_size,
                              hipStream_t stream) {
    const float* inputs = (const float*)d_in[0];  // [4096][256]
    const float* dw     = (const float*)d_in[1];  // [256][6][256]
    const float* thr    = (const float*)d_in[2];  // [256][6]
    const float* leaf   = (const float*)d_in[3];  // [256][64]
    float* out = (float*)d_out;                   // [4096]
    float* ws  = (float*)d_ws;

    // prep: 4096 + 1536 + 64 + 24 = 5720 waves, 4 waves/block -> 1430 blocks
    prep_kernel<<<1430, 256, 0, stream>>>(inputs, dw, thr, leaf, ws);

    // forest: 4096 / BPB = 512 blocks of 256 threads
    forest_kernel<<<BATCH / BPB, 256, 0, stream>>>(ws, out);
}